// Round 7
// baseline (321.021 us; speedup 1.0000x reference)
//
#include <hip/hip_runtime.h>
#include <hip/hip_cooperative_groups.h>

namespace cg = cooperative_groups;

#define NUM_FINE 1048576
#define NF 128
#define NUM_SEG 262144

#define SB 256   // setup grid blocks  (co-resident: 1 per CU)
#define ST 512   // setup block threads

typedef float f32x4 __attribute__((ext_vector_type(4)));

// ---- Fused setup: zero -> count(+rank in regs) -> scan -> place ----
__global__ void fused_setup(const int* __restrict__ ids, int* __restrict__ cnt,
                            int* __restrict__ blockSums, int* __restrict__ base,
                            int* __restrict__ perm, int2* __restrict__ desc) {
    cg::grid_group grid = cg::this_grid();
    __shared__ int lds[ST];
    const int tid = threadIdx.x, bid = blockIdx.x;
    const int gt = bid * ST + tid;              // 0 .. 131071

    // A: zero cnt (2 ints/thread, 256K total)
    *reinterpret_cast<int2*>(cnt + gt * 2) = make_int2(0, 0);

    // load this thread's 8 ids into registers while the zeroing drains
    int myids[8];
    const int ibase = gt * 8;
    int4 a0 = *reinterpret_cast<const int4*>(ids + ibase);
    int4 a1 = *reinterpret_cast<const int4*>(ids + ibase + 4);
    myids[0] = a0.x; myids[1] = a0.y; myids[2] = a0.z; myids[3] = a0.w;
    myids[4] = a1.x; myids[5] = a1.y; myids[6] = a1.z; myids[7] = a1.w;

    grid.sync();  // cnt zeroed everywhere

    // B: histogram + within-segment rank (kept in registers; no global rank array)
    int myrank[8];
#pragma unroll
    for (int k = 0; k < 8; ++k) myrank[k] = atomicAdd(&cnt[myids[k]], 1);

    grid.sync();  // all counts final

    // C1: per-block scan of 1024 counts (2/thread)
    const int g = bid * 1024 + tid * 2;
    int2 c2 = *reinterpret_cast<const int2*>(cnt + g);
    int s = c2.x + c2.y;
    lds[tid] = s;
    __syncthreads();
    for (int off = 1; off < ST; off <<= 1) {
        int v = (tid >= off) ? lds[tid - off] : 0;
        __syncthreads();
        lds[tid] += v;
        __syncthreads();
    }
    int excl = lds[tid] - s;
    if (tid == 0) blockSums[bid] = lds[ST - 1];
    grid.sync();  // all block sums visible

    // C2: every block redundantly scans the 256 block sums, picks its prefix
    {
        int v = (tid < SB) ? blockSums[tid] : 0;
        __syncthreads();
        lds[tid] = v;
        __syncthreads();
        for (int off = 1; off < SB; off <<= 1) {
            int t = (tid >= off && tid < SB) ? lds[tid - off] : 0;
            __syncthreads();
            if (tid < SB) lds[tid] += t;
            __syncthreads();
        }
        int add = (bid > 0) ? lds[bid - 1] : 0;
        int b0 = excl + add;
        int b1 = b0 + c2.x;
        *reinterpret_cast<int2*>(base + g) = make_int2(b0, b1);
        *reinterpret_cast<int4*>(desc + g) = make_int4(b0, c2.x, b1, c2.y);
    }
    grid.sync();  // base final

    // D: place (atomic-free; ids+ranks still in registers)
#pragma unroll
    for (int k = 0; k < 8; ++k) {
        perm[base[myids[k]] + myrank[k]] = ibase + k;
    }
}

// One clamped, masked row-pair load: unconditional (keeps MLP), in-instruction
// duplicates coalesce to the same line (free).
__device__ __forceinline__ f32x4 rowld(const float* __restrict__ x,
                                       const int* __restrict__ perm,
                                       int j, int end, int last, int f) {
    int jj = (j < end) ? j : last;
    int row = perm[jj];
    f32x4 v = *reinterpret_cast<const f32x4*>(x + (size_t)row * NF + f);
    float m = (j < end) ? 1.f : 0.f;
    return v * m;
}

// ---- Gather: one wave per segment; lane holds float4 (2 rows per load
// instruction). Wave-uniform case ladder sizes the issued batch to c. ----
__global__ void gather_kernel(const float* __restrict__ x,
                              const int* __restrict__ perm,
                              const int2* __restrict__ desc,
                              float* __restrict__ out) {
    int wid = (blockIdx.x << 2) | (threadIdx.x >> 6);  // segment id
    int lane = threadIdx.x & 63;
    int h = lane >> 5;           // which row of the pair this half-wave reads
    int f = (lane & 31) << 2;    // feature offset (float4)
    int2 d = desc[wid];
    int start = d.x, c = d.y;
    int end = start + c, last = end - 1;
    f32x4 acc = {0.f, 0.f, 0.f, 0.f};
    if (c > 0) {
        if (c <= 2) {
            acc = rowld(x, perm, start + h, end, last, f);
        } else if (c <= 4) {
            acc = rowld(x, perm, start + h,     end, last, f)
                + rowld(x, perm, start + 2 + h, end, last, f);
        } else if (c <= 6) {
            acc = rowld(x, perm, start + h,     end, last, f)
                + rowld(x, perm, start + 2 + h, end, last, f)
                + rowld(x, perm, start + 4 + h, end, last, f);
        } else if (c <= 8) {
            acc = rowld(x, perm, start + h,     end, last, f)
                + rowld(x, perm, start + 2 + h, end, last, f)
                + rowld(x, perm, start + 4 + h, end, last, f)
                + rowld(x, perm, start + 6 + h, end, last, f);
        } else {
            for (int r = start; r < end; r += 8) {
                acc += rowld(x, perm, r + h,     end, last, f)
                     + rowld(x, perm, r + 2 + h, end, last, f)
                     + rowld(x, perm, r + 4 + h, end, last, f)
                     + rowld(x, perm, r + 6 + h, end, last, f);
            }
        }
        acc.x += __shfl_xor(acc.x, 32);
        acc.y += __shfl_xor(acc.y, 32);
        acc.z += __shfl_xor(acc.z, 32);
        acc.w += __shfl_xor(acc.w, 32);
    }
    if (h == 0) {
        float inv = 1.0f / (float)(c > 1 ? c : 1);   // c==0 -> acc==0 -> writes 0
        f32x4 o = acc * inv;
        *reinterpret_cast<f32x4*>(out + (size_t)wid * NF + f) = o;
    }
}

extern "C" void kernel_launch(void* const* d_in, const int* in_sizes, int n_in,
                              void* d_out, int out_size, void* d_ws, size_t ws_size,
                              hipStream_t stream) {
    const float* x   = (const float*)d_in[0];
    const int*   ids = (const int*)d_in[1];
    float* out = (float*)d_out;

    char* ws = (char*)d_ws;
    int*  cnt       = (int*)(ws);               // 1 MiB
    int*  base      = (int*)(ws + (1 << 20));   // 1 MiB
    int*  blockSums = (int*)(ws + (2 << 20));   // 1 KiB
    int2* desc      = (int2*)(ws + (3 << 20));  // 2 MiB
    int*  perm      = (int*)(ws + (5 << 20));   // 4 MiB

    void* args[] = {(void*)&ids, (void*)&cnt, (void*)&blockSums,
                    (void*)&base, (void*)&perm, (void*)&desc};
    hipLaunchCooperativeKernel((const void*)fused_setup, dim3(SB), dim3(ST),
                               args, 0, stream);

    // 1 wave per segment, 4 waves per block
    gather_kernel<<<NUM_SEG / 4, 256, 0, stream>>>(x, perm, desc, out);
}

// Round 8
// 207.370 us; speedup vs baseline: 1.5481x; 1.5481x over previous
//
#include <hip/hip_runtime.h>

#define NUM_FINE 1048576
#define NF 128
#define NUM_SEG 262144

typedef float f32x4 __attribute__((ext_vector_type(4)));

// ---- Phase 1: histogram + within-segment rank ----
__global__ void count_rank_kernel(const int* __restrict__ ids, int* __restrict__ cnt,
                                  int* __restrict__ rank) {
    int i = (blockIdx.x * blockDim.x + threadIdx.x) * 4;
    int4 a = *reinterpret_cast<const int4*>(ids + i);
    int4 r;
    r.x = atomicAdd(&cnt[a.x], 1);
    r.y = atomicAdd(&cnt[a.y], 1);
    r.z = atomicAdd(&cnt[a.z], 1);
    r.w = atomicAdd(&cnt[a.w], 1);
    *reinterpret_cast<int4*>(rank + i) = r;
}

// ---- Phase 2a: per-block exclusive scan (1024 elems/block via int4) ----
__global__ void scan1_kernel(const int* __restrict__ cnt, int* __restrict__ base,
                             int* __restrict__ blockSums) {
    __shared__ int lds[256];
    int tid = threadIdx.x;
    int g = blockIdx.x * 1024 + tid * 4;
    int4 a = *reinterpret_cast<const int4*>(cnt + g);
    int s = a.x + a.y + a.z + a.w;
    lds[tid] = s;
    __syncthreads();
    for (int off = 1; off < 256; off <<= 1) {
        int v = (tid >= off) ? lds[tid - off] : 0;
        __syncthreads();
        lds[tid] += v;
        __syncthreads();
    }
    int excl = lds[tid] - s;
    int4 o;
    o.x = excl;
    o.y = o.x + a.x;
    o.z = o.y + a.y;
    o.w = o.z + a.z;
    *reinterpret_cast<int4*>(base + g) = o;
    if (tid == 255) blockSums[blockIdx.x] = lds[255];
}

// ---- Phase 2b: re-scan block sums in LDS, finalize base, emit (start,cnt) desc ----
__global__ void scan3_kernel(int* __restrict__ base, const int* __restrict__ blockSums,
                             const int* __restrict__ cnt, int2* __restrict__ desc) {
    __shared__ int lds[256];
    int tid = threadIdx.x;
    int v = blockSums[tid];
    lds[tid] = v;
    __syncthreads();
    for (int off = 1; off < 256; off <<= 1) {
        int t = (tid >= off) ? lds[tid - off] : 0;
        __syncthreads();
        lds[tid] += t;
        __syncthreads();
    }
    int add = (blockIdx.x > 0) ? lds[blockIdx.x - 1] : 0;  // LDS broadcast
    int g = blockIdx.x * 1024 + tid * 4;
    int4 b = *reinterpret_cast<int4*>(base + g);
    int4 cc = *reinterpret_cast<const int4*>(cnt + g);
    b.x += add; b.y += add; b.z += add; b.w += add;
    *reinterpret_cast<int4*>(base + g) = b;
    *reinterpret_cast<int4*>(desc + g)     = make_int4(b.x, cc.x, b.y, cc.y);
    *reinterpret_cast<int4*>(desc + g + 2) = make_int4(b.z, cc.z, b.w, cc.w);
}

// ---- Phase 3: placement, atomic-free (rank precomputed) ----
__global__ void place_kernel(const int* __restrict__ ids, const int* __restrict__ base,
                             const int* __restrict__ rank, int* __restrict__ perm) {
    int i = (blockIdx.x * blockDim.x + threadIdx.x) * 4;
    int4 a = *reinterpret_cast<const int4*>(ids + i);
    int4 r = *reinterpret_cast<const int4*>(rank + i);
    perm[base[a.x] + r.x] = i;
    perm[base[a.y] + r.y] = i + 1;
    perm[base[a.z] + r.z] = i + 2;
    perm[base[a.w] + r.w] = i + 3;
}

__device__ __forceinline__ f32x4 rowx(const float* __restrict__ x, int row, int f) {
    return *reinterpret_cast<const f32x4*>(x + (size_t)row * NF + f);
}

// ---- Phase 4: gather. One wave per segment; lane holds float4 (2 rows per
// load instruction). perm entries for the segment are CONTIGUOUS: lanes 0-7
// prefetch up to 8 of them in ONE coalesced load; row indices are then
// distributed by __shfl (no further vmem). Wave-uniform case ladder sizes
// the issued row batch to c. ----
__global__ void gather_kernel(const float* __restrict__ x,
                              const int* __restrict__ perm,
                              const int2* __restrict__ desc,
                              float* __restrict__ out) {
    int wid = (blockIdx.x << 2) | (threadIdx.x >> 6);  // segment id
    int lane = threadIdx.x & 63;
    int h = lane >> 5;           // which row of the pair this half-wave reads
    int f = (lane & 31) << 2;    // feature offset (float4)
    int2 d = desc[wid];
    int start = d.x, c = d.y;
    f32x4 acc = {0.f, 0.f, 0.f, 0.f};
    if (c > 0) {
        int pl = lane & 7;       // perm slot this lane prefetches (replicated x8)
        int pv = perm[start + ((pl < c) ? pl : (c - 1))];
        int r0 = __shfl(pv, h);  // row j = h (always valid: h <= 1 <= c-? masked below)
        if (c <= 2) {
            f32x4 v0 = rowx(x, r0, f);
            float m0 = (h < c) ? 1.f : 0.f;
            acc = v0 * m0;
        } else if (c <= 4) {
            int r1 = __shfl(pv, 2 + h);
            f32x4 v0 = rowx(x, r0, f);
            f32x4 v1 = rowx(x, r1, f);
            float m1 = (2 + h < c) ? 1.f : 0.f;
            acc = v0 + v1 * m1;
        } else if (c <= 6) {
            int r1 = __shfl(pv, 2 + h);
            int r2 = __shfl(pv, 4 + h);
            f32x4 v0 = rowx(x, r0, f);
            f32x4 v1 = rowx(x, r1, f);
            f32x4 v2 = rowx(x, r2, f);
            float m2 = (4 + h < c) ? 1.f : 0.f;
            acc = v0 + v1 + v2 * m2;
        } else if (c <= 8) {
            int r1 = __shfl(pv, 2 + h);
            int r2 = __shfl(pv, 4 + h);
            int r3 = __shfl(pv, 6 + h);
            f32x4 v0 = rowx(x, r0, f);
            f32x4 v1 = rowx(x, r1, f);
            f32x4 v2 = rowx(x, r2, f);
            f32x4 v3 = rowx(x, r3, f);
            float m3 = (6 + h < c) ? 1.f : 0.f;
            acc = v0 + v1 + v2 + v3 * m3;
        } else {
            int end = start + c;
            for (int r = start; r < end; r += 8) {
                int pj = r + pl;
                pv = perm[(pj < end) ? pj : (end - 1)];
                int q0 = __shfl(pv, h);
                int q1 = __shfl(pv, 2 + h);
                int q2 = __shfl(pv, 4 + h);
                int q3 = __shfl(pv, 6 + h);
                f32x4 v0 = rowx(x, q0, f);
                f32x4 v1 = rowx(x, q1, f);
                f32x4 v2 = rowx(x, q2, f);
                f32x4 v3 = rowx(x, q3, f);
                int rem = end - r;
                float m0 = (h < rem)     ? 1.f : 0.f;
                float m1 = (2 + h < rem) ? 1.f : 0.f;
                float m2 = (4 + h < rem) ? 1.f : 0.f;
                float m3 = (6 + h < rem) ? 1.f : 0.f;
                acc += v0 * m0 + v1 * m1 + v2 * m2 + v3 * m3;
            }
        }
        acc.x += __shfl_xor(acc.x, 32);
        acc.y += __shfl_xor(acc.y, 32);
        acc.z += __shfl_xor(acc.z, 32);
        acc.w += __shfl_xor(acc.w, 32);
    }
    if (h == 0) {
        float inv = 1.0f / (float)(c > 1 ? c : 1);   // c==0 -> acc==0 -> writes 0
        f32x4 o = acc * inv;
        *reinterpret_cast<f32x4*>(out + (size_t)wid * NF + f) = o;
    }
}

extern "C" void kernel_launch(void* const* d_in, const int* in_sizes, int n_in,
                              void* d_out, int out_size, void* d_ws, size_t ws_size,
                              hipStream_t stream) {
    const float* x   = (const float*)d_in[0];
    const int*   ids = (const int*)d_in[1];
    float* out = (float*)d_out;

    char* ws = (char*)d_ws;
    int*  cnt       = (int*)(ws);                       // 1 MiB
    int*  base      = (int*)(ws + (1 << 20));           // 1 MiB
    int*  blockSums = (int*)(ws + (2 << 20));           // 1 KiB
    int*  perm      = (int*)(ws + (3 << 20));           // 4 MiB
    int*  rank      = (int*)(ws + (7 << 20));           // 4 MiB
    int2* desc      = (int2*)(ws + (11 << 20));         // 2 MiB

    hipMemsetAsync(cnt, 0, (size_t)NUM_SEG * sizeof(int), stream);

    count_rank_kernel<<<NUM_FINE / 1024, 256, 0, stream>>>(ids, cnt, rank);
    scan1_kernel<<<NUM_SEG / 1024, 256, 0, stream>>>(cnt, base, blockSums);
    scan3_kernel<<<NUM_SEG / 1024, 256, 0, stream>>>(base, blockSums, cnt, desc);
    place_kernel<<<NUM_FINE / 1024, 256, 0, stream>>>(ids, base, rank, perm);

    // 1 wave per segment, 4 waves per block
    gather_kernel<<<NUM_SEG / 4, 256, 0, stream>>>(x, perm, desc, out);
}